// Round 6
// baseline (115.410 us; speedup 1.0000x reference)
//
#include <hip/hip_runtime.h>
#include <math.h>

// GaussianMixture log-density via f16 MFMA, fused single kernel, round 6.
//
//   e[k,n] = sum_j C[k][j] * F[j][n]   (base-2 exponent, fp32 MFMA accum)
//     coeff row  (A operand, LDS):  [ a2[0..19] , b2[0..19] , L2 , 0.. ]
//     feature col(B operand, regs): [ x^2_0..19 , x_0..19 , 1 , 0.. ]
//   out[n] = ln( sum_k exp2(e[k,n]) ) + LOG_NORM
//
// R6: loop nest inverted vs R5. All 8 chunks' feature fragments are packed
// once into 16 named f16x8 SSA values (64 VGPRs); the tile loop then reads
// each LDS coefficient fragment ONCE and feeds 8 MFMAs. LDS pipe traffic
// drops 8x (was ~9.4 us of per-CU LDS bandwidth floor in R5).

#define DIMS     20
#define MULT     8
#define K_COMP   168
#define KC_PAD   176            // 11 tiles of 16 components
#define BROW     72             // halfs per coeff row: 144 B stride
#define BASE_COV 0.1f
#define LOG2E    1.4426950408889634f
#define LN2      0.6931471805599453f
#define LOG_NORM -18.378770664093453f
#define CPW      8              // 16-sample chunks per wave
#define NB       1024           // NB * 4 waves * CPW * 16 = 524288 exactly

typedef _Float16 f16x8 __attribute__((ext_vector_type(8)));
typedef _Float16 f16x2 __attribute__((ext_vector_type(2)));
typedef float    f32x4 __attribute__((ext_vector_type(4)));
typedef unsigned int uint;
typedef uint u32x4 __attribute__((ext_vector_type(4)));

__device__ __forceinline__ uint pk(float lo, float hi) {
    return __builtin_bit_cast(uint, __builtin_amdgcn_cvt_pkrtz(lo, hi));
}
__device__ __forceinline__ uint pksq(uint a) {     // v_pk_mul_f16: (lo^2, hi^2)
    f16x2 v = __builtin_bit_cast(f16x2, a);
    return __builtin_bit_cast(uint, (f16x2)(v * v));
}

__global__ __launch_bounds__(256) void gm_fused(const float* __restrict__ sample,
                                                const float* __restrict__ alpha,
                                                const float* __restrict__ mu,
                                                const float* __restrict__ cov,
                                                float* __restrict__ out) {
    __shared__ __attribute__((aligned(16))) _Float16 lds_T[KC_PAD][BROW];
    __shared__ float sh_logZ;
    const int tid = threadIdx.x;

    // ---- phase 1: zero the coefficient table ----
    uint* bz = (uint*)&lds_T[0][0];
    for (int i = tid; i < KC_PAD * BROW / 2; i += 256) bz[i] = 0u;
    __syncthreads();

    // ---- phase 2: softmax normalizer (wave 0) ----
    if (tid < 64) {
        float a0 = (tid       < K_COMP) ? alpha[tid]       : -1e30f;
        float a1 = (tid + 64  < K_COMP) ? alpha[tid + 64]  : -1e30f;
        float a2 = (tid + 128 < K_COMP) ? alpha[tid + 128] : -1e30f;
        float m = fmaxf(fmaxf(a0, a1), a2);
        for (int msk = 32; msk; msk >>= 1) m = fmaxf(m, __shfl_xor(m, msk, 64));
        float s = __expf(a0 - m) + __expf(a1 - m) + __expf(a2 - m);
        for (int msk = 32; msk; msk >>= 1) s += __shfl_xor(s, msk, 64);
        if (tid == 0) sh_logZ = m + __logf(s);
    }
    __syncthreads();

    // ---- phase 3: fill coefficient rows (one thread per component) ----
    if (tid < K_COMP) {
        const int   n  = tid;
        const int   i  = n / MULT;
        const float fi = (float)i;
        const float var = 1.0f;                       // EPS^2, EPS = 1.0
        float logdet = fi * __logf(var) + ((float)DIMS - fi) * __logf(BASE_COV);
        const float4* cvp = (const float4*)(cov + n * DIMS);
        const float4* mup = (const float4*)(mu + n * DIMS);
        float4 c0 = cvp[0], c1 = cvp[1], c2 = cvp[2], c3 = cvp[3], c4 = cvp[4];
        float4 m0 = mup[0], m1 = mup[1], m2 = mup[2], m3 = mup[3], m4 = mup[4];
        float C = 0.0f;
        auto emit = [&](int d, float cc, float mm) {
            float scale = (d < i) ? var : 1.0f;
            float inv   = 1.0f / (cc * scale);
            C += mm * mm * inv;
            lds_T[n][d]        = (_Float16)(-0.5f * inv * LOG2E);
            lds_T[n][DIMS + d] = (_Float16)(mm * inv * LOG2E);
        };
        emit( 0, c0.x, m0.x); emit( 1, c0.y, m0.y); emit( 2, c0.z, m0.z); emit( 3, c0.w, m0.w);
        emit( 4, c1.x, m1.x); emit( 5, c1.y, m1.y); emit( 6, c1.z, m1.z); emit( 7, c1.w, m1.w);
        emit( 8, c2.x, m2.x); emit( 9, c2.y, m2.y); emit(10, c2.z, m2.z); emit(11, c2.w, m2.w);
        emit(12, c3.x, m3.x); emit(13, c3.y, m3.y); emit(14, c3.z, m3.z); emit(15, c3.w, m3.w);
        emit(16, c4.x, m4.x); emit(17, c4.y, m4.y); emit(18, c4.z, m4.z); emit(19, c4.w, m4.w);
        float L2 = ((alpha[n] - sh_logZ) - 0.5f * logdet - 0.5f * C) * LOG2E;
        lds_T[n][2 * DIMS] = (_Float16)L2;
    } else if (tid < KC_PAD) {
        lds_T[tid][2 * DIMS] = (_Float16)(-65504.0f); // pad comps -> exp2 -> 0
    }
    __syncthreads();

    // ---- phase 4: pack all CPW chunks' feature fragments into registers ----
    const int w = tid >> 6, l = tid & 63, q = l >> 4, c = l & 15;
    const bool qa = (q & 1) != 0, qb = (q & 2) != 0;
    const uint onezero = 0x00003C00u;                 // pk(1.0h, 0.0h)
    const f32x4 zero = { 0.f, 0.f, 0.f, 0.f };
    const int base = blockIdx.x * (64 * CPW) + w * 16 + c;

    // B-fragment: frag1 pair v = p[q*4+v], frag2 pair v = p[16+q*4+v],
    // p = [s0..s9 (x^2 pairs), q0..q9 (x pairs), onezero, 0...]
#define MAKE_FRAGS(CC)                                                          \
    f16x8 sf1_##CC, sf2_##CC;                                                   \
    {                                                                           \
        const float4* rp = (const float4*)(sample + (size_t)(base + (CC) * 64) * DIMS); \
        float4 r0 = rp[0], r1 = rp[1], r2 = rp[2], r3 = rp[3], r4 = rp[4];      \
        uint q0 = pk(r0.x, r0.y), q1 = pk(r0.z, r0.w);                          \
        uint q2 = pk(r1.x, r1.y), q3 = pk(r1.z, r1.w);                          \
        uint q4 = pk(r2.x, r2.y), q5 = pk(r2.z, r2.w);                          \
        uint q6 = pk(r3.x, r3.y), q7 = pk(r3.z, r3.w);                          \
        uint q8 = pk(r4.x, r4.y), q9 = pk(r4.z, r4.w);                          \
        uint s0 = pksq(q0), s1 = pksq(q1), s2 = pksq(q2), s3 = pksq(q3);        \
        uint s4 = pksq(q4), s5 = pksq(q5), s6 = pksq(q6), s7 = pksq(q7);        \
        uint s8 = pksq(q8), s9 = pksq(q9);                                      \
        uint f1_0 = qb ? (qa ? q2 : s8) : (qa ? s4 : s0);                       \
        uint f1_1 = qb ? (qa ? q3 : s9) : (qa ? s5 : s1);                       \
        uint f1_2 = qb ? (qa ? q4 : q0) : (qa ? s6 : s2);                       \
        uint f1_3 = qb ? (qa ? q5 : q1) : (qa ? s7 : s3);                       \
        uint f2_0 = qb ? 0u : (qa ? onezero : q6);                              \
        uint f2_1 = qb ? 0u : (qa ? 0u : q7);                                   \
        uint f2_2 = qb ? 0u : (qa ? 0u : q8);                                   \
        uint f2_3 = qb ? 0u : (qa ? 0u : q9);                                   \
        u32x4 w1 = { f1_0, f1_1, f1_2, f1_3 };                                  \
        u32x4 w2 = { f2_0, f2_1, f2_2, f2_3 };                                  \
        sf1_##CC = __builtin_bit_cast(f16x8, w1);                               \
        sf2_##CC = __builtin_bit_cast(f16x8, w2);                               \
    }

    MAKE_FRAGS(0) MAKE_FRAGS(1) MAKE_FRAGS(2) MAKE_FRAGS(3)
    MAKE_FRAGS(4) MAKE_FRAGS(5) MAKE_FRAGS(6) MAKE_FRAGS(7)
#undef MAKE_FRAGS

    // ---- phase 5: tiles outer, chunks inner -- each LDS fragment read once ----
    float d0 = 0.f, d1 = 0.f, d2 = 0.f, d3 = 0.f;
    float d4 = 0.f, d5 = 0.f, d6 = 0.f, d7 = 0.f;
#pragma unroll
    for (int t = 0; t < KC_PAD / 16; ++t) {
        f16x8 cf1 = *(const f16x8*)&lds_T[t * 16 + c][q * 8];
        f16x8 cf2 = *(const f16x8*)&lds_T[t * 16 + c][32 + q * 8];
#define DO_CHUNK(CC)                                                            \
        {                                                                       \
            f32x4 acc = __builtin_amdgcn_mfma_f32_16x16x32_f16(cf1, sf1_##CC, zero, 0, 0, 0); \
            acc       = __builtin_amdgcn_mfma_f32_16x16x32_f16(cf2, sf2_##CC, acc,  0, 0, 0); \
            d##CC += (__builtin_amdgcn_exp2f(acc[0]) + __builtin_amdgcn_exp2f(acc[1]))        \
                   + (__builtin_amdgcn_exp2f(acc[2]) + __builtin_amdgcn_exp2f(acc[3]));       \
        }
        DO_CHUNK(0) DO_CHUNK(1) DO_CHUNK(2) DO_CHUNK(3)
        DO_CHUNK(4) DO_CHUNK(5) DO_CHUNK(6) DO_CHUNK(7)
#undef DO_CHUNK
    }

    // ---- phase 6: reduce over component-group quads, store ----
    const int ob = blockIdx.x * (64 * CPW) + w * 16;
#define FINISH(CC, DD)                                                          \
    {                                                                           \
        float dn = DD;                                                          \
        dn += __shfl_xor(dn, 16, 64);                                           \
        dn += __shfl_xor(dn, 32, 64);                                           \
        if (l < 16) out[ob + (CC) * 64 + l] = LN2 * __builtin_amdgcn_logf(dn) + LOG_NORM; \
    }
    FINISH(0, d0) FINISH(1, d1) FINISH(2, d2) FINISH(3, d3)
    FINISH(4, d4) FINISH(5, d5) FINISH(6, d6) FINISH(7, d7)
#undef FINISH
}

extern "C" void kernel_launch(void* const* d_in, const int* in_sizes, int n_in,
                              void* d_out, int out_size, void* d_ws, size_t ws_size,
                              hipStream_t stream) {
    const float* sample = (const float*)d_in[0];
    const float* alpha  = (const float*)d_in[1];
    const float* mu     = (const float*)d_in[2];
    const float* cov    = (const float*)d_in[3];
    float* out = (float*)d_out;
    // N = 524288 = NB * 4 waves * CPW * 16 -- grid covers the range exactly.
    gm_fused<<<NB, 256, 0, stream>>>(sample, alpha, mu, cov, out);
}

// Round 7
// 96.056 us; speedup vs baseline: 1.2015x; 1.2015x over previous
//
#include <hip/hip_runtime.h>
#include <math.h>

// GaussianMixture log-density via f16 MFMA, fused single kernel, round 7.
//
//   e[k,n] = sum_j C[k][j] * F[j][n]   (base-2 exponent, fp32 MFMA accum)
//     coeff row  (A operand):  [ a2[0..19] , b2[0..19] , L2 , 0.. ]
//     feature col(B operand):  [ x^2_0..19 , x_0..19 , 1 , 0.. ]
//   out[n] = ln( sum_k exp2(e[k,n]) ) + LOG_NORM
//
// R6 lesson: tile-outer kept 16 sample fragments + 40 in-flight float4 loads
// live -> 192 VGPR -> 2 waves/SIMD -> latency-bound (52 us).
// R7: hoist the COEFFICIENTS instead -- each lane's 11-tile A-fragments are
// only 22 f16x8 = 88 VGPRs, read from LDS once; chunks processed serially so
// sample live-range stays ~1 chunk. launch_bounds(256,3) pins 3 waves/SIMD.

#define DIMS     20
#define MULT     8
#define K_COMP   168
#define KC_PAD   176            // 11 tiles of 16 components
#define BROW     72             // halfs per coeff row: 144 B stride
#define BASE_COV 0.1f
#define LOG2E    1.4426950408889634f
#define LN2      0.6931471805599453f
#define LOG_NORM -18.378770664093453f
#define CPW      8              // 16-sample chunks per wave
#define NB       1024           // NB * 4 waves * CPW * 16 = 524288 exactly

typedef _Float16 f16x8 __attribute__((ext_vector_type(8)));
typedef _Float16 f16x2 __attribute__((ext_vector_type(2)));
typedef float    f32x4 __attribute__((ext_vector_type(4)));
typedef unsigned int uint;
typedef uint u32x4 __attribute__((ext_vector_type(4)));

__device__ __forceinline__ uint pk(float lo, float hi) {
    return __builtin_bit_cast(uint, __builtin_amdgcn_cvt_pkrtz(lo, hi));
}
__device__ __forceinline__ uint pksq(uint a) {     // v_pk_mul_f16: (lo^2, hi^2)
    f16x2 v = __builtin_bit_cast(f16x2, a);
    return __builtin_bit_cast(uint, (f16x2)(v * v));
}

__global__ __launch_bounds__(256, 3) void gm_fused(const float* __restrict__ sample,
                                                   const float* __restrict__ alpha,
                                                   const float* __restrict__ mu,
                                                   const float* __restrict__ cov,
                                                   float* __restrict__ out) {
    __shared__ __attribute__((aligned(16))) _Float16 lds_T[KC_PAD][BROW];
    __shared__ float sh_logZ;
    const int tid = threadIdx.x;

    // ---- phase 1: zero the coefficient table ----
    uint* bz = (uint*)&lds_T[0][0];
    for (int i = tid; i < KC_PAD * BROW / 2; i += 256) bz[i] = 0u;
    __syncthreads();

    // ---- phase 2: softmax normalizer (wave 0) ----
    if (tid < 64) {
        float a0 = (tid       < K_COMP) ? alpha[tid]       : -1e30f;
        float a1 = (tid + 64  < K_COMP) ? alpha[tid + 64]  : -1e30f;
        float a2 = (tid + 128 < K_COMP) ? alpha[tid + 128] : -1e30f;
        float m = fmaxf(fmaxf(a0, a1), a2);
        for (int msk = 32; msk; msk >>= 1) m = fmaxf(m, __shfl_xor(m, msk, 64));
        float s = __expf(a0 - m) + __expf(a1 - m) + __expf(a2 - m);
        for (int msk = 32; msk; msk >>= 1) s += __shfl_xor(s, msk, 64);
        if (tid == 0) sh_logZ = m + __logf(s);
    }
    __syncthreads();

    // ---- phase 3: fill coefficient rows (one thread per component) ----
    if (tid < K_COMP) {
        const int   n  = tid;
        const int   i  = n / MULT;
        const float fi = (float)i;
        const float var = 1.0f;                       // EPS^2, EPS = 1.0
        float logdet = fi * __logf(var) + ((float)DIMS - fi) * __logf(BASE_COV);
        const float4* cvp = (const float4*)(cov + n * DIMS);
        const float4* mup = (const float4*)(mu + n * DIMS);
        float4 c0 = cvp[0], c1 = cvp[1], c2 = cvp[2], c3 = cvp[3], c4 = cvp[4];
        float4 m0 = mup[0], m1 = mup[1], m2 = mup[2], m3 = mup[3], m4 = mup[4];
        float C = 0.0f;
        auto emit = [&](int d, float cc, float mm) {
            float scale = (d < i) ? var : 1.0f;
            float inv   = 1.0f / (cc * scale);
            C += mm * mm * inv;
            lds_T[n][d]        = (_Float16)(-0.5f * inv * LOG2E);
            lds_T[n][DIMS + d] = (_Float16)(mm * inv * LOG2E);
        };
        emit( 0, c0.x, m0.x); emit( 1, c0.y, m0.y); emit( 2, c0.z, m0.z); emit( 3, c0.w, m0.w);
        emit( 4, c1.x, m1.x); emit( 5, c1.y, m1.y); emit( 6, c1.z, m1.z); emit( 7, c1.w, m1.w);
        emit( 8, c2.x, m2.x); emit( 9, c2.y, m2.y); emit(10, c2.z, m2.z); emit(11, c2.w, m2.w);
        emit(12, c3.x, m3.x); emit(13, c3.y, m3.y); emit(14, c3.z, m3.z); emit(15, c3.w, m3.w);
        emit(16, c4.x, m4.x); emit(17, c4.y, m4.y); emit(18, c4.z, m4.z); emit(19, c4.w, m4.w);
        float L2 = ((alpha[n] - sh_logZ) - 0.5f * logdet - 0.5f * C) * LOG2E;
        lds_T[n][2 * DIMS] = (_Float16)L2;
    } else if (tid < KC_PAD) {
        lds_T[tid][2 * DIMS] = (_Float16)(-65504.0f); // pad comps -> exp2 -> 0
    }
    __syncthreads();

    // ---- phase 4: hoist coefficient fragments into registers (88 VGPRs) ----
    const int w = tid >> 6, l = tid & 63, q = l >> 4, c = l & 15;
    const bool qa = (q & 1) != 0, qb = (q & 2) != 0;
    const uint onezero = 0x00003C00u;                 // pk(1.0h, 0.0h)
    const f32x4 zero = { 0.f, 0.f, 0.f, 0.f };

#define LOAD_CF(T)                                                              \
    const f16x8 cf1_##T = *(const f16x8*)&lds_T[(T) * 16 + c][q * 8];           \
    const f16x8 cf2_##T = *(const f16x8*)&lds_T[(T) * 16 + c][32 + q * 8];
    LOAD_CF(0) LOAD_CF(1) LOAD_CF(2) LOAD_CF(3) LOAD_CF(4) LOAD_CF(5)
    LOAD_CF(6) LOAD_CF(7) LOAD_CF(8) LOAD_CF(9) LOAD_CF(10)
#undef LOAD_CF

    // ---- phase 5: chunks serial; coeff regs reused by all 8 chunks ----
    const int base = blockIdx.x * (64 * CPW) + w * 16;

#define DO_TILE(T)                                                              \
        {                                                                       \
            f32x4 acc = __builtin_amdgcn_mfma_f32_16x16x32_f16(cf1_##T, sf1, zero, 0, 0, 0); \
            acc       = __builtin_amdgcn_mfma_f32_16x16x32_f16(cf2_##T, sf2, acc,  0, 0, 0); \
            dens += (__builtin_amdgcn_exp2f(acc[0]) + __builtin_amdgcn_exp2f(acc[1]))        \
                  + (__builtin_amdgcn_exp2f(acc[2]) + __builtin_amdgcn_exp2f(acc[3]));       \
        }

#define DO_CHUNK(CC)                                                            \
    {                                                                           \
        const float4* rp = (const float4*)(sample + (size_t)(base + (CC) * 64 + c) * DIMS); \
        float4 r0 = rp[0], r1 = rp[1], r2 = rp[2], r3 = rp[3], r4 = rp[4];      \
        uint q0 = pk(r0.x, r0.y), q1 = pk(r0.z, r0.w);                          \
        uint q2 = pk(r1.x, r1.y), q3 = pk(r1.z, r1.w);                          \
        uint q4 = pk(r2.x, r2.y), q5 = pk(r2.z, r2.w);                          \
        uint q6 = pk(r3.x, r3.y), q7 = pk(r3.z, r3.w);                          \
        uint q8 = pk(r4.x, r4.y), q9 = pk(r4.z, r4.w);                          \
        uint s0 = pksq(q0), s1 = pksq(q1), s2 = pksq(q2), s3 = pksq(q3);        \
        uint s4 = pksq(q4), s5 = pksq(q5), s6 = pksq(q6), s7 = pksq(q7);        \
        uint s8 = pksq(q8), s9 = pksq(q9);                                      \
        uint f1_0 = qb ? (qa ? q2 : s8) : (qa ? s4 : s0);                       \
        uint f1_1 = qb ? (qa ? q3 : s9) : (qa ? s5 : s1);                       \
        uint f1_2 = qb ? (qa ? q4 : q0) : (qa ? s6 : s2);                       \
        uint f1_3 = qb ? (qa ? q5 : q1) : (qa ? s7 : s3);                       \
        uint f2_0 = qb ? 0u : (qa ? onezero : q6);                              \
        uint f2_1 = qb ? 0u : (qa ? 0u : q7);                                   \
        uint f2_2 = qb ? 0u : (qa ? 0u : q8);                                   \
        uint f2_3 = qb ? 0u : (qa ? 0u : q9);                                   \
        u32x4 w1 = { f1_0, f1_1, f1_2, f1_3 };                                  \
        u32x4 w2 = { f2_0, f2_1, f2_2, f2_3 };                                  \
        f16x8 sf1 = __builtin_bit_cast(f16x8, w1);                              \
        f16x8 sf2 = __builtin_bit_cast(f16x8, w2);                              \
        float dens = 0.0f;                                                      \
        DO_TILE(0) DO_TILE(1) DO_TILE(2) DO_TILE(3) DO_TILE(4) DO_TILE(5)       \
        DO_TILE(6) DO_TILE(7) DO_TILE(8) DO_TILE(9) DO_TILE(10)                 \
        dens += __shfl_xor(dens, 16, 64);                                       \
        dens += __shfl_xor(dens, 32, 64);                                       \
        if (l < 16)                                                             \
            out[base + (CC) * 64 + l] = LN2 * __builtin_amdgcn_logf(dens) + LOG_NORM; \
    }

    DO_CHUNK(0) DO_CHUNK(1) DO_CHUNK(2) DO_CHUNK(3)
    DO_CHUNK(4) DO_CHUNK(5) DO_CHUNK(6) DO_CHUNK(7)
#undef DO_CHUNK
#undef DO_TILE
}

extern "C" void kernel_launch(void* const* d_in, const int* in_sizes, int n_in,
                              void* d_out, int out_size, void* d_ws, size_t ws_size,
                              hipStream_t stream) {
    const float* sample = (const float*)d_in[0];
    const float* alpha  = (const float*)d_in[1];
    const float* mu     = (const float*)d_in[2];
    const float* cov    = (const float*)d_in[3];
    float* out = (float*)d_out;
    // N = 524288 = NB * 4 waves * CPW * 16 -- grid covers the range exactly.
    gm_fused<<<NB, 256, 0, stream>>>(sample, alpha, mu, cov, out);
}